// Round 2
// baseline (665.946 us; speedup 1.0000x reference)
//
#include <hip/hip_runtime.h>
#include <math.h>

#define NH    12
#define SEQ   1024
#define DH    64
#define HID   768
#define BATCH 16
#define MTOT  (BATCH*SEQ)   // 16384
#define KDIM  HID           // 768

typedef __attribute__((ext_vector_type(8))) short short8;
typedef __attribute__((ext_vector_type(4))) short short4v;
typedef __attribute__((ext_vector_type(8))) unsigned short ushort8;
typedef __attribute__((ext_vector_type(4))) float float4v;

__device__ __forceinline__ float bf2f(unsigned short u) {
    union { unsigned int i; float f; } v; v.i = ((unsigned int)u) << 16; return v.f;
}
__device__ __forceinline__ unsigned short f2bf(float f) {
    union { float f; unsigned int i; } v; v.f = f;
    unsigned int x = v.i;
    return (unsigned short)((x + 0x7FFFu + ((x >> 16) & 1u)) >> 16);  // RNE
}
__device__ __forceinline__ float loadf(const void* p, size_t i, bool f32) {
    return f32 ? ((const float*)p)[i] : bf2f(((const unsigned short*)p)[i]);
}
// HW packed f32->bf16 (RNE), 2 floats -> 1 dword {hi16=b, lo16=a}
__device__ __forceinline__ unsigned int cvt_pk_bf16(float a, float b) {
    unsigned int r;
    asm("v_cvt_pk_bf16_f32 %0, %1, %2" : "=v"(r) : "v"(a), "v"(b));
    return r;
}
__device__ __forceinline__ float fast_exp2(float x) {
#if __has_builtin(__builtin_amdgcn_exp2f)
    return __builtin_amdgcn_exp2f(x);
#else
    return exp2f(x);
#endif
}

// async global->LDS, 16B/lane; LDS dest = wave-uniform base + lane*16.
__device__ __forceinline__ void gload_lds16(const void* g, void* l) {
    __builtin_amdgcn_global_load_lds(
        (const __attribute__((address_space(1))) unsigned int*)g,
        (__attribute__((address_space(3))) unsigned int*)l, 16, 0, 0);
}

// Runtime dtype classifier for x (flag=1 => fp32 inputs).
__global__ __launch_bounds__(256) void detect_kernel(
    const unsigned short* __restrict__ x, unsigned int* __restrict__ flag)
{
    __shared__ int cnt[256];
    const int tid = threadIdx.x;
    int local = 0;
    for (int i = tid; i < 1024; i += 256) {
        const unsigned short u = x[i];
        const int e = (u >> 7) & 0xFF;
        if ((e >= 96 && e <= 134) || ((u & 0x7FFF) == 0)) local++;
    }
    cnt[tid] = local;
    __syncthreads();
    for (int s = 128; s > 0; s >>= 1) {
        if (tid < s) cnt[tid] += cnt[tid + s];
        __syncthreads();
    }
    if (tid == 0) flag[0] = (cnt[0] < 900) ? 1u : 0u;
}

// Elementwise Ootomo split src -> hi (+ lo), N elems, 8/thread.
template<bool LO>
__global__ __launch_bounds__(256) void split_ker(
    const void* __restrict__ src, const unsigned int* __restrict__ flag,
    unsigned short* __restrict__ hi, unsigned short* __restrict__ lo, int n)
{
    const size_t i = ((size_t)blockIdx.x * 256 + threadIdx.x) * 8;
    if (i >= (size_t)n) return;
    ushort8 h, l;
    if (flag[0]) {
        const float* fp = (const float*)src + i;
        float4v f0 = *(const float4v*)fp, f1 = *(const float4v*)(fp + 4);
#pragma unroll
        for (int e = 0; e < 4; e++) {
            unsigned short h0 = f2bf(f0[e]), h1 = f2bf(f1[e]);
            h[e] = h0; h[4 + e] = h1;
            if (LO) { l[e] = f2bf(f0[e] - bf2f(h0)); l[4 + e] = f2bf(f1[e] - bf2f(h1)); }
        }
    } else {
        h = *(const ushort8*)((const unsigned short*)src + i);
        if (LO) {
#pragma unroll
            for (int e = 0; e < 8; e++) l[e] = 0;
        }
    }
    *(ushort8*)(hi + i) = h;
    if (LO) *(ushort8*)(lo + i) = l;
}

// W fragment load with in-register split (fallback path, W L2-resident).
template<bool WF32, bool PRECISE>
__device__ __forceinline__ void loadW(const void* __restrict__ W, size_t idx,
                                      short8& hi, short8& lo) {
    if constexpr (WF32) {
        const float* fp = (const float*)W + idx;
        float4v f0 = *(const float4v*)fp, f1 = *(const float4v*)(fp + 4);
#pragma unroll
        for (int e = 0; e < 4; e++) {
            unsigned short h0 = f2bf(f0[e]), h1 = f2bf(f1[e]);
            hi[e] = (short)h0; hi[4 + e] = (short)h1;
            if constexpr (PRECISE) {
                lo[e] = (short)f2bf(f0[e] - bf2f(h0));
                lo[4 + e] = (short)f2bf(f1[e] - bf2f(h1));
            }
        }
    } else {
        hi = *(const short8*)((const unsigned short*)W + idx);
        if constexpr (PRECISE) {
#pragma unroll
            for (int e = 0; e < 8; e++) lo[e] = 0;
        }
    }
}

// K-loop v2: double-buffered LDS staging. Stage for tile k+1 is issued
// BEFORE compute on tile k; the single end-of-iter __syncthreads (implied
// vmcnt(0)) drains the PREFETCH, whose latency is covered by the 16-48
// MFMAs + W loads of the current tile. One barrier per K-step (was two,
// with the current tile's stage latency fully exposed).
template<bool PRECISE, bool WPRE, bool WF32>
__device__ __forceinline__ void staged_kloop(
    const unsigned short* __restrict__ Ahi, const unsigned short* __restrict__ Alo,
    const void* __restrict__ Wa, const void* __restrict__ Wb,
    unsigned short* sAhi, unsigned short* sAlo,   // [2][128*32] ushorts each
    int m_blk0, int n_base, int wid, int lane, float4v acc[4][4])
{
    const int tid  = wid * 64 + lane;
    const int quad = lane >> 4, l16 = lane & 15;
    const int m_off = (wid >> 1) * 64;
    const int srow = tid >> 2;
    const int scc  = tid & 3;

    auto stage = [&](int k0, int b) {
#pragma unroll
        for (int it = 0; it < 2; it++) {
            const int r = it * 64 + srow;
            const size_t gidx = (size_t)(m_blk0 + r) * KDIM + k0 + scc * 8;
            const int loff = b * 4096 + r * 32 + scc * 8;
            gload_lds16(Ahi + gidx, sAhi + loff);
            if constexpr (PRECISE) gload_lds16(Alo + gidx, sAlo + loff);
        }
    };

    stage(0, 0);
    __syncthreads();

    for (int k0 = 0; k0 < KDIM; k0 += 32) {
        const int b = (k0 >> 5) & 1;
        if (k0 + 32 < KDIM) stage(k0 + 32, b ^ 1);

        short8 bh[4], bl[4];
#pragma unroll
        for (int in = 0; in < 4; in++) {
            const size_t widx = (size_t)(n_base + in * 16 + l16) * KDIM + k0 + quad * 8;
            if constexpr (WPRE) {
                bh[in] = *(const short8*)((const unsigned short*)Wa + widx);
                if constexpr (PRECISE)
                    bl[in] = *(const short8*)((const unsigned short*)Wb + widx);
            } else {
                loadW<WF32, PRECISE>(Wa, widx, bh[in], bl[in]);
            }
        }
        short8 ah[4], al[4];
#pragma unroll
        for (int im = 0; im < 4; im++) {
            const int r = m_off + im * 16 + l16;
            ah[im] = *(const short8*)(sAhi + b * 4096 + r * 32 + quad * 8);
            if constexpr (PRECISE) al[im] = *(const short8*)(sAlo + b * 4096 + r * 32 + quad * 8);
        }
#pragma unroll
        for (int im = 0; im < 4; im++)
#pragma unroll
            for (int in = 0; in < 4; in++) {
                acc[im][in] = __builtin_amdgcn_mfma_f32_16x16x32_bf16(
                    ah[im], bh[in], acc[im][in], 0, 0, 0);
                if constexpr (PRECISE) {
                    acc[im][in] = __builtin_amdgcn_mfma_f32_16x16x32_bf16(
                        al[im], bh[in], acc[im][in], 0, 0, 0);
                    acc[im][in] = __builtin_amdgcn_mfma_f32_16x16x32_bf16(
                        ah[im], bl[in], acc[im][in], 0, 0, 0);
                }
            }
        __syncthreads();   // drains prefetch (vmcnt0) + protects buf b for reuse
    }
}

// MODE 0: precise, +bias +rope *0.125*log2(e) -> hi/lo bf16 (B,H,S,D)  (Q)
// MODE 1: precise, +bias +rope               -> hi/lo bf16 (B,H,S,D)  (K)
// MODE 2: fast,    +bias                     -> bf16 V^T (B,H,D,S)
// MODE 3: fast,    +bias                     -> d_out (M,N), dtype per flag
template<int MODE, bool WPRE>
__device__ __forceinline__ void gemm_body(
    const unsigned short* __restrict__ Ahi, const unsigned short* __restrict__ Alo,
    const void* __restrict__ Wa, const void* __restrict__ Wb,
    const void* __restrict__ bias,
    const void* __restrict__ cosc, const void* __restrict__ sinc,
    const unsigned int* __restrict__ flag,
    void* __restrict__ Out, void* __restrict__ Out2,
    unsigned short* sAhi, unsigned short* sAlo,
    int m_blk0, int ny)
{
    constexpr bool PRECISE = (MODE <= 1);
    const int tid  = threadIdx.x;
    const int wid  = tid >> 6;
    const int lane = tid & 63;
    const int quad = lane >> 4;
    const int l16  = lane & 15;
    const int m_blk = m_blk0 + (wid >> 1) * 64;
    const int n_base = ny * 128 + (wid & 1) * 64;
    const bool f32 = (flag[0] != 0u);

    float4v acc[4][4];
#pragma unroll
    for (int i = 0; i < 4; i++)
#pragma unroll
        for (int j = 0; j < 4; j++) acc[i][j] = (float4v)(0.f);

    if constexpr (WPRE) {
        staged_kloop<PRECISE, true, false>(Ahi, Alo, Wa, Wb, sAhi, sAlo,
                                           m_blk0, n_base, wid, lane, acc);
    } else {
        if (f32) staged_kloop<PRECISE, false, true >(Ahi, Alo, Wa, Wb, sAhi, sAlo,
                                                     m_blk0, n_base, wid, lane, acc);
        else     staged_kloop<PRECISE, false, false>(Ahi, Alo, Wa, Wb, sAhi, sAlo,
                                                     m_blk0, n_base, wid, lane, acc);
    }

#pragma unroll
    for (int im = 0; im < 4; im++) {
#pragma unroll
        for (int in = 0; in < 4; in++) {
            const int col = n_base + in * 16 + l16;
            const float bval = loadf(bias, col, f32);
            if constexpr (MODE == 2) {
                short4v pk;
#pragma unroll
                for (int r = 0; r < 4; r++)
                    pk[r] = (short)f2bf(acc[im][in][r] + bval);
                const int row = m_blk + im * 16 + quad * 4;
                const int b = row >> 10, s = row & (SEQ - 1);
                const int h = col >> 6, d = col & (DH - 1);
                *(short4v*)((unsigned short*)Out +
                    ((size_t)(b * NH + h) * DH + d) * SEQ + s) = pk;
            } else if constexpr (MODE <= 1) {
                const int d  = col & (DH - 1);
                const int d2 = d >> 1;
#pragma unroll
                for (int r = 0; r < 4; r++) {
                    const int row = m_blk + im * 16 + quad * 4 + r;
                    const int s  = row & (SEQ - 1);
                    const float v = acc[im][in][r] + bval;
                    const float c  = loadf(cosc, s * (DH / 2) + d2, f32);
                    const float sn = loadf(sinc, s * (DH / 2) + d2, f32);
                    const float p = __shfl_xor(v, 1);  // lane^1 <-> d^1
                    float o = (d & 1) ? (v * c + p * sn) : (v * c - p * sn);
                    // Q scale folded with log2(e): logits live in log2 domain
                    if (MODE == 0) o *= 0.18033688f;   // 0.125 * 1.44269504
                    const float po = __shfl_xor(o, 1);
                    if (!(l16 & 1)) {
                        const unsigned short h0 = f2bf(o), h1 = f2bf(po);
                        const unsigned short l0 = f2bf(o - bf2f(h0));
                        const unsigned short l1 = f2bf(po - bf2f(h1));
                        const int b = row >> 10, h = col >> 6;
                        const size_t idx = ((size_t)(b * NH + h) * SEQ + s) * DH + d;
                        *(unsigned int*)((unsigned short*)Out + idx) =
                            (unsigned int)h0 | ((unsigned int)h1 << 16);
                        *(unsigned int*)((unsigned short*)Out2 + idx) =
                            (unsigned int)l0 | ((unsigned int)l1 << 16);
                    }
                }
            } else {
#pragma unroll
                for (int r = 0; r < 4; r++) {
                    const int row = m_blk + im * 16 + quad * 4 + r;
                    const float v = acc[im][in][r] + bval;
                    if (f32) ((float*)Out)[(size_t)row * HID + col] = v;
                    else     ((unsigned short*)Out)[(size_t)row * HID + col] = f2bf(v);
                }
            }
        }
    }
}

template<int MODE, bool WPRE>
__global__ __launch_bounds__(256) void gemm_staged(
    const unsigned short* __restrict__ Ahi, const unsigned short* __restrict__ Alo,
    const void* __restrict__ Wa, const void* __restrict__ Wb,
    const void* __restrict__ bias,
    const void* __restrict__ cosc, const void* __restrict__ sinc,
    const unsigned int* __restrict__ flag,
    void* __restrict__ Out, void* __restrict__ Out2)
{
    constexpr bool PRECISE = (MODE <= 1);
    __shared__ unsigned short sAhi[2 * 4096];
    __shared__ unsigned short sAlo[PRECISE ? 2 * 4096 : 64];
    gemm_body<MODE, WPRE>(Ahi, Alo, Wa, Wb, bias, cosc, sinc, flag, Out, Out2,
                          sAhi, sAlo, blockIdx.x * 128, blockIdx.y);
}

// Fused QKV GEMM: grid (M/128, 18); blockIdx.y/6 selects Q/K/V, %6 is the
// N-block. 2304 blocks (vs 3x768) — tail smoothing + concurrent A reuse in
// L2/L3 + 2 fewer launch gaps. Requires V^T buffer NOT aliasing Xlo
// (Xlo is live as the A-lo operand of the concurrent Q/K blocks).
template<bool WPRE>
__global__ __launch_bounds__(256) void gemm_qkv(
    const unsigned short* __restrict__ Ahi, const unsigned short* __restrict__ Alo,
    const void* __restrict__ Wqa, const void* __restrict__ Wqb,
    const void* __restrict__ Wka, const void* __restrict__ Wkb,
    const void* __restrict__ Wva,
    const void* __restrict__ bq, const void* __restrict__ bk,
    const void* __restrict__ bv,
    const void* __restrict__ cosc, const void* __restrict__ sinc,
    const unsigned int* __restrict__ flag,
    void* __restrict__ Qhi, void* __restrict__ Qlo,
    void* __restrict__ Khi, void* __restrict__ Klo,
    void* __restrict__ Vt)
{
    __shared__ unsigned short sAhi[2 * 4096];
    __shared__ unsigned short sAlo[2 * 4096];
    const int which = blockIdx.y / 6;
    const int ny    = blockIdx.y % 6;
    const int m0    = blockIdx.x * 128;
    if (which == 0)
        gemm_body<0, WPRE>(Ahi, Alo, Wqa, Wqb, bq, cosc, sinc, flag,
                           Qhi, Qlo, sAhi, sAlo, m0, ny);
    else if (which == 1)
        gemm_body<1, WPRE>(Ahi, Alo, Wka, Wkb, bk, cosc, sinc, flag,
                           Khi, Klo, sAhi, sAlo, m0, ny);
    else
        gemm_body<2, WPRE>(Ahi, nullptr, Wva, nullptr, bv, nullptr, nullptr, flag,
                           Vt, nullptr, sAhi, sAlo, m0, ny);
}

// MFMA RSE attention v4: 4 waves/block, 64q each (256 q/block, 768 blocks).
// K/V per 32-key chunk staged ONCE per block via global_load_lds into a
// double-buffered, XOR-swizzled LDS slab; fragments via ds_read_b128.
// P routing is fully in-register: v_cvt_pk_bf16_f32 pack + permlane16/32
// swaps transpose {lane bits 4,5} <-> {register bits kt,h} — no P LDS slab,
// no software f2bf in the hot loop. Logits are computed in the log2 domain
// (log2e folded into the Q scale at GEMM time).
__global__ __launch_bounds__(256, 2) void attn_mfma(
    const unsigned short* __restrict__ Qhi, const unsigned short* __restrict__ Qlo,
    const unsigned short* __restrict__ Khi, const unsigned short* __restrict__ Klo,
    const unsigned short* __restrict__ Vt,   // (B*H, D, S) bf16
    const void* __restrict__ lam_p, const unsigned int* __restrict__ flag,
    unsigned short* __restrict__ ctx)        // (B, S, HID) bf16
{
    const int tid  = threadIdx.x;
    const int wid  = tid >> 6;
    const int lane = tid & 63;
    const int quad = lane >> 4;
    const int l16  = lane & 15;
    const int phys = blockIdx.x;                   // 768 blocks
    const int virt = (phys & 7) * 96 + (phys >> 3);  // XCD-contiguous bh runs
    const int bh   = virt >> 2;                    // 4 q-blocks per bh
    const int q0   = (virt & 3) * 256 + wid * 64;  // wave's query base
    const bool f32 = (flag[0] != 0u);
    // lam scaled into the log2 domain to match the pre-scaled Q
    const float lam2 = loadf(lam_p, 0, f32) * 1.44269504f;

    // [buf][ Khi 2048 | Klo 2048 | V 2048 ] ushorts (12KB per buffer)
    __shared__ unsigned short KV[2][6144];

    // staging thread mapping (whole block stages 12KB in 3 issues/thread)
    const int krow = tid >> 3, kch = tid & 7;
    const int kgch = kch ^ (krow & 7);             // XOR swizzle (read-side spread)
    const int vrow = tid >> 2, vch = tid & 3;
    const int vgch = vch ^ (vrow & 3);

    #define STAGE(kb_, buf_) do {                                            \
        const size_t gk = ((size_t)bh * SEQ + (kb_) * 32 + krow) * DH + kgch * 8; \
        gload_lds16(Khi + gk, &KV[buf_][0]    + tid * 8);                    \
        gload_lds16(Klo + gk, &KV[buf_][2048] + tid * 8);                    \
        const size_t gv = ((size_t)bh * DH + vrow) * SEQ + (kb_) * 32 + vgch * 8; \
        gload_lds16(Vt + gv, &KV[buf_][4096] + tid * 8);                     \
    } while (0)

    // resident Q fragments (B-operand), hi+lo
    short8 qh[4][2], ql[4][2];
#pragma unroll
    for (int qn = 0; qn < 4; qn++)
#pragma unroll
        for (int ks = 0; ks < 2; ks++) {
            const size_t base = ((size_t)bh * SEQ + (q0 + qn * 16 + l16)) * DH
                                + ks * 32 + quad * 8;
            qh[qn][ks] = *(const short8*)(Qhi + base);
            ql[qn][ks] = *(const short8*)(Qlo + base);
        }

    float4v acc_o[4][4];
#pragma unroll
    for (int i = 0; i < 4; i++)
#pragma unroll
        for (int j = 0; j < 4; j++) acc_o[i][j] = (float4v)(0.f);

    float rem[4] = {1.f, 1.f, 1.f, 1.f};
    float l_i[4] = {0.f, 0.f, 0.f, 0.f};
    float m_i[4] = {-INFINITY, -INFINITY, -INFINITY, -INFINITY};
    float qf[4];
#pragma unroll
    for (int qn = 0; qn < 4; qn++) qf[qn] = (float)(q0 + qn * 16 + l16);

    STAGE(0, 0);
    __syncthreads();

    for (int kb = 0; kb < SEQ / 32; kb++) {
        const int buf = kb & 1;
        if (kb + 1 < SEQ / 32) STAGE(kb + 1, buf ^ 1);

        // ---- K fragments from LDS (swizzled) ----
        short8 kh[2][2], kl[2][2];
#pragma unroll
        for (int kt = 0; kt < 2; kt++)
#pragma unroll
            for (int ks = 0; ks < 2; ks++) {
                const int off = (kt * 16 + l16) * 64
                                + ((ks * 4 + quad) ^ (l16 & 7)) * 8;
                kh[kt][ks] = *(const short8*)(&KV[buf][0]    + off);
                kl[kt][ks] = *(const short8*)(&KV[buf][2048] + off);
            }

        // ---- S^T = K·Q^T (bf16x3), log2-domain logits ----
        float4v s[2][4];
#pragma unroll
        for (int kt = 0; kt < 2; kt++)
#pragma unroll
            for (int qn = 0; qn < 4; qn++) s[kt][qn] = (float4v)(0.f);
#pragma unroll
        for (int ks = 0; ks < 2; ks++)
#pragma unroll
            for (int kt = 0; kt < 2; kt++)
#pragma unroll
                for (int qn = 0; qn < 4; qn++) {
                    s[kt][qn] = __builtin_amdgcn_mfma_f32_16x16x32_bf16(
                        kh[kt][ks], qh[qn][ks], s[kt][qn], 0, 0, 0);
                    s[kt][qn] = __builtin_amdgcn_mfma_f32_16x16x32_bf16(
                        kl[kt][ks], qh[qn][ks], s[kt][qn], 0, 0, 0);
                    s[kt][qn] = __builtin_amdgcn_mfma_f32_16x16x32_bf16(
                        kh[kt][ks], ql[qn][ks], s[kt][qn], 0, 0, 0);
                }

        // ---- sigmoid / decay / stats (log2 domain: no per-elem mul) ----
        float cons[4] = {0.f, 0.f, 0.f, 0.f};
        float mx[4] = {-INFINITY, -INFINITY, -INFINITY, -INFINITY};
#pragma unroll
        for (int kt = 0; kt < 2; kt++)
#pragma unroll
            for (int qn = 0; qn < 4; qn++)
#pragma unroll
                for (int r = 0; r < 4; r++) {
                    const float keyf = (float)(kb * 32 + kt * 16 + quad * 4 + r);
                    const float logit = s[kt][qn][r] - lam2 * fabsf(qf[qn] - keyf);
                    mx[qn] = fmaxf(mx[qn], logit);
                    const float beta = __builtin_amdgcn_rcpf(
                        1.f + fast_exp2(-logit));
                    const float w = beta * rem[qn];
                    cons[qn] += w;
                    s[kt][qn][r] = w;
                }
#pragma unroll
        for (int qn = 0; qn < 4; qn++) {
            cons[qn] += __shfl_xor(cons[qn], 16);
            cons[qn] += __shfl_xor(cons[qn], 32);
            mx[qn] = fmaxf(mx[qn], __shfl_xor(mx[qn], 16));
            mx[qn] = fmaxf(mx[qn], __shfl_xor(mx[qn], 32));
        }

        // ---- P^T B-fragments fully in-register ----
        short8 pf[4];
#pragma unroll
        for (int qn = 0; qn < 4; qn++) {
            const unsigned int d00 = cvt_pk_bf16(s[0][qn][0], s[0][qn][1]); // kt0 h0
            const unsigned int d01 = cvt_pk_bf16(s[0][qn][2], s[0][qn][3]); // kt0 h1
            const unsigned int d10 = cvt_pk_bf16(s[1][qn][0], s[1][qn][1]); // kt1 h0
            const unsigned int d11 = cvt_pk_bf16(s[1][qn][2], s[1][qn][3]); // kt1 h1
            auto r0 = __builtin_amdgcn_permlane32_swap(d00, d10, false, false);
            auto r1 = __builtin_amdgcn_permlane32_swap(d01, d11, false, false);
            auto t0 = __builtin_amdgcn_permlane16_swap(r0[0], r0[1], false, false);
            auto t1 = __builtin_amdgcn_permlane16_swap(r1[0], r1[1], false, false);
            union { unsigned int u[4]; short8 s8; } cv;
            cv.u[0] = t0[0];  // keys quad*8+{0,1}
            cv.u[1] = t1[0];  // keys quad*8+{2,3}
            cv.u[2] = t0[1];  // keys quad*8+{4,5}
            cv.u[3] = t1[1];  // keys quad*8+{6,7}
            pf[qn] = cv.s8;
        }

        // ---- O^T += V^T·P^T ----
        short8 vf[4];
#pragma unroll
        for (int dt = 0; dt < 4; dt++) {
            const int off = (dt * 16 + l16) * 32 + (quad ^ (l16 & 3)) * 8;
            vf[dt] = *(const short8*)(&KV[buf][4096] + off);
        }
#pragma unroll
        for (int dt = 0; dt < 4; dt++)
#pragma unroll
            for (int jn = 0; jn < 4; jn++)
                acc_o[dt][jn] = __builtin_amdgcn_mfma_f32_16x16x32_bf16(
                    vf[dt], pf[jn], acc_o[dt][jn], 0, 0, 0);

        // ---- state update (alpha converted back to raw-logit domain) ----
#pragma unroll
        for (int qn = 0; qn < 4; qn++) {
            rem[qn] = fmaxf(rem[qn] * (1.f - cons[qn]), 1e-6f);
            const float m_new = fmaxf(m_i[qn], mx[qn]);
            const float alpha = fast_exp2((m_i[qn] - m_new) * 0.69314718f);
            l_i[qn] = l_i[qn] * alpha + cons[qn];
            m_i[qn] = m_new;
        }

        __syncthreads();   // drains stage(kb+1) loads; protects buf reuse
    }

    const int b = bh / NH, h = bh % NH;
    float inv[4];
#pragma unroll
    for (int jn = 0; jn < 4; jn++)
        inv[jn] = __builtin_amdgcn_rcpf(fmaxf(l_i[jn], 1e-6f));
#pragma unroll
    for (int dt = 0; dt < 4; dt++)
#pragma unroll
        for (int jn = 0; jn < 4; jn++) {
            short4v pk;
#pragma unroll
            for (int r = 0; r < 4; r++)
                pk[r] = (short)f2bf(acc_o[dt][jn][r] * inv[jn]);
            const int q_g = q0 + jn * 16 + l16;
            *(short4v*)(ctx + ((size_t)(b * SEQ + q_g) * HID
                               + h * DH + dt * 16 + quad * 4)) = pk;
        }
    #undef STAGE
}

extern "C" void kernel_launch(void* const* d_in, const int* in_sizes, int n_in,
                              void* d_out, int out_size, void* d_ws, size_t ws_size,
                              hipStream_t stream) {
    const void* x    = d_in[0];
    const void* Wq   = d_in[1];
    const void* bq   = d_in[2];
    const void* Wk   = d_in[3];
    const void* bk   = d_in[4];
    const void* Wv   = d_in[5];
    const void* bv   = d_in[6];
    const void* Wo   = d_in[7];
    const void* bo   = d_in[8];
    const void* lam  = d_in[9];
    const void* cosc = d_in[10];
    const void* sinc = d_in[11];

    const size_t NELEM = (size_t)MTOT * HID;   // 12.58M
    const size_t WELEM = (size_t)HID * HID;    // 589824
    unsigned int* flag = (unsigned int*)d_ws;
    unsigned short* Xhi = (unsigned short*)((char*)d_ws + 64);
    unsigned short* Xlo = Xhi + NELEM;
    unsigned short* Qhi = Xlo + NELEM;
    unsigned short* Qlo = Qhi + NELEM;
    unsigned short* Wqh = Qlo + NELEM;   // W splits
    unsigned short* Wql = Wqh + WELEM;
    unsigned short* Wkh = Wql + WELEM;
    unsigned short* Wkl = Wkh + WELEM;
    unsigned short* Wvh = Wkl + WELEM;
    unsigned short* Woh = Wvh + WELEM;
    unsigned short* VtF = Woh + WELEM;   // fused-path V^T (must not alias Xlo)
    const size_t NEED  = 64 + 4 * NELEM * 2 + 6 * WELEM * 2;
    const size_t NEEDF = NEED + NELEM * 2;
    const bool wpre = (ws_size >= NEED);
    const bool fuse = (ws_size >= NEEDF);  // fuse implies wpre

    unsigned short* Vt  = fuse ? VtF : Xlo;  // sequential path: xlo dead after K GEMM
    unsigned short* Ctx = Xhi;               // xhi dead after V GEMM
    unsigned short* Khi = (unsigned short*)d_out;  // dead before final GEMM
    unsigned short* Klo = Khi + NELEM;

    detect_kernel<<<1, 256, 0, stream>>>((const unsigned short*)x, flag);
    split_ker<true><<<(MTOT * KDIM) / 2048, 256, 0, stream>>>(x, flag, Xhi, Xlo, MTOT * KDIM);

    dim3 gg(MTOT / 128, HID / 128), gb(256);
    if (fuse) {
        const int wb = (int)(WELEM / 2048);
        split_ker<true ><<<wb, 256, 0, stream>>>(Wq, flag, Wqh, Wql, (int)WELEM);
        split_ker<true ><<<wb, 256, 0, stream>>>(Wk, flag, Wkh, Wkl, (int)WELEM);
        split_ker<false><<<wb, 256, 0, stream>>>(Wv, flag, Wvh, nullptr, (int)WELEM);
        split_ker<false><<<wb, 256, 0, stream>>>(Wo, flag, Woh, nullptr, (int)WELEM);
        gemm_qkv<true><<<dim3(MTOT / 128, 18), gb, 0, stream>>>(
            Xhi, Xlo, Wqh, Wql, Wkh, Wkl, Wvh, bq, bk, bv,
            cosc, sinc, flag, Qhi, Qlo, Khi, Klo, VtF);
    } else if (wpre) {
        const int wb = (int)(WELEM / 2048);
        split_ker<true ><<<wb, 256, 0, stream>>>(Wq, flag, Wqh, Wql, (int)WELEM);
        split_ker<true ><<<wb, 256, 0, stream>>>(Wk, flag, Wkh, Wkl, (int)WELEM);
        split_ker<false><<<wb, 256, 0, stream>>>(Wv, flag, Wvh, nullptr, (int)WELEM);
        split_ker<false><<<wb, 256, 0, stream>>>(Wo, flag, Woh, nullptr, (int)WELEM);
        gemm_staged<0, true><<<gg, gb, 0, stream>>>(Xhi, Xlo, Wqh, Wql, bq, cosc, sinc, flag, Qhi, Qlo);
        gemm_staged<1, true><<<gg, gb, 0, stream>>>(Xhi, Xlo, Wkh, Wkl, bk, cosc, sinc, flag, Khi, Klo);
        gemm_staged<2, true><<<gg, gb, 0, stream>>>(Xhi, nullptr, Wvh, nullptr, bv, nullptr, nullptr, flag, Vt, nullptr);
    } else {
        gemm_staged<0, false><<<gg, gb, 0, stream>>>(Xhi, Xlo, Wq, nullptr, bq, cosc, sinc, flag, Qhi, Qlo);
        gemm_staged<1, false><<<gg, gb, 0, stream>>>(Xhi, Xlo, Wk, nullptr, bk, cosc, sinc, flag, Khi, Klo);
        gemm_staged<2, false><<<gg, gb, 0, stream>>>(Xhi, nullptr, Wv, nullptr, bv, nullptr, nullptr, flag, Vt, nullptr);
    }
    attn_mfma<<<dim3(4 * BATCH * NH), 256, 0, stream>>>(
        Qhi, Qlo, Khi, Klo, Vt, lam, flag, Ctx);
    if (wpre)
        gemm_staged<3, true><<<gg, gb, 0, stream>>>(Ctx, nullptr, Woh, nullptr, bo, nullptr, nullptr, flag, d_out, nullptr);
    else
        gemm_staged<3, false><<<gg, gb, 0, stream>>>(Ctx, nullptr, Wo, nullptr, bo, nullptr, nullptr, flag, d_out, nullptr);
}

// Round 3
// 554.260 us; speedup vs baseline: 1.2015x; 1.2015x over previous
//
#include <hip/hip_runtime.h>
#include <math.h>

#define NH    12
#define SEQ   1024
#define DH    64
#define HID   768
#define BATCH 16
#define MTOT  (BATCH*SEQ)   // 16384
#define KDIM  HID           // 768

typedef __attribute__((ext_vector_type(8))) short short8;
typedef __attribute__((ext_vector_type(4))) short short4v;
typedef __attribute__((ext_vector_type(8))) unsigned short ushort8;
typedef __attribute__((ext_vector_type(4))) float float4v;

__device__ __forceinline__ float bf2f(unsigned short u) {
    union { unsigned int i; float f; } v; v.i = ((unsigned int)u) << 16; return v.f;
}
__device__ __forceinline__ unsigned short f2bf(float f) {
    union { float f; unsigned int i; } v; v.f = f;
    unsigned int x = v.i;
    return (unsigned short)((x + 0x7FFFu + ((x >> 16) & 1u)) >> 16);  // RNE
}
__device__ __forceinline__ float loadf(const void* p, size_t i, bool f32) {
    return f32 ? ((const float*)p)[i] : bf2f(((const unsigned short*)p)[i]);
}
// HW packed f32->bf16 (RNE), 2 floats -> 1 dword {hi16=b, lo16=a}
__device__ __forceinline__ unsigned int cvt_pk_bf16(float a, float b) {
    unsigned int r;
    asm("v_cvt_pk_bf16_f32 %0, %1, %2" : "=v"(r) : "v"(a), "v"(b));
    return r;
}
__device__ __forceinline__ float fast_exp2(float x) {
#if __has_builtin(__builtin_amdgcn_exp2f)
    return __builtin_amdgcn_exp2f(x);
#else
    return exp2f(x);
#endif
}

// async global->LDS, 16B/lane; LDS dest = wave-uniform base + lane*16.
__device__ __forceinline__ void gload_lds16(const void* g, void* l) {
    __builtin_amdgcn_global_load_lds(
        (const __attribute__((address_space(1))) unsigned int*)g,
        (__attribute__((address_space(3))) unsigned int*)l, 16, 0, 0);
}

// Runtime dtype classifier for x (flag=1 => fp32 inputs).
__global__ __launch_bounds__(256) void detect_kernel(
    const unsigned short* __restrict__ x, unsigned int* __restrict__ flag)
{
    __shared__ int cnt[256];
    const int tid = threadIdx.x;
    int local = 0;
    for (int i = tid; i < 1024; i += 256) {
        const unsigned short u = x[i];
        const int e = (u >> 7) & 0xFF;
        if ((e >= 96 && e <= 134) || ((u & 0x7FFF) == 0)) local++;
    }
    cnt[tid] = local;
    __syncthreads();
    for (int s = 128; s > 0; s >>= 1) {
        if (tid < s) cnt[tid] += cnt[tid + s];
        __syncthreads();
    }
    if (tid == 0) flag[0] = (cnt[0] < 900) ? 1u : 0u;
}

// Elementwise Ootomo split src -> hi (+ lo), N elems, 8/thread.
template<bool LO>
__global__ __launch_bounds__(256) void split_ker(
    const void* __restrict__ src, const unsigned int* __restrict__ flag,
    unsigned short* __restrict__ hi, unsigned short* __restrict__ lo, int n)
{
    const size_t i = ((size_t)blockIdx.x * 256 + threadIdx.x) * 8;
    if (i >= (size_t)n) return;
    ushort8 h, l;
    if (flag[0]) {
        const float* fp = (const float*)src + i;
        float4v f0 = *(const float4v*)fp, f1 = *(const float4v*)(fp + 4);
#pragma unroll
        for (int e = 0; e < 4; e++) {
            unsigned short h0 = f2bf(f0[e]), h1 = f2bf(f1[e]);
            h[e] = h0; h[4 + e] = h1;
            if (LO) { l[e] = f2bf(f0[e] - bf2f(h0)); l[4 + e] = f2bf(f1[e] - bf2f(h1)); }
        }
    } else {
        h = *(const ushort8*)((const unsigned short*)src + i);
        if (LO) {
#pragma unroll
            for (int e = 0; e < 8; e++) l[e] = 0;
        }
    }
    *(ushort8*)(hi + i) = h;
    if (LO) *(ushort8*)(lo + i) = l;
}

// W fragment load with in-register split (fallback path, W L2-resident).
template<bool WF32, bool PRECISE>
__device__ __forceinline__ void loadW(const void* __restrict__ W, size_t idx,
                                      short8& hi, short8& lo) {
    if constexpr (WF32) {
        const float* fp = (const float*)W + idx;
        float4v f0 = *(const float4v*)fp, f1 = *(const float4v*)(fp + 4);
#pragma unroll
        for (int e = 0; e < 4; e++) {
            unsigned short h0 = f2bf(f0[e]), h1 = f2bf(f1[e]);
            hi[e] = (short)h0; hi[4 + e] = (short)h1;
            if constexpr (PRECISE) {
                lo[e] = (short)f2bf(f0[e] - bf2f(h0));
                lo[4 + e] = (short)f2bf(f1[e] - bf2f(h1));
            }
        }
    } else {
        hi = *(const short8*)((const unsigned short*)W + idx);
        if constexpr (PRECISE) {
#pragma unroll
            for (int e = 0; e < 8; e++) lo[e] = 0;
        }
    }
}

// K-loop v3: counted-vmcnt pipeline (T3/T4), 3 LDS buffers, 2-deep prefetch.
//
// vmcnt is IN-ORDER: to keep the prefetch in flight across the MFMA phase,
// the stage for tile k+2 must be the YOUNGEST vmem op when the MFMAs wait
// for the W register loads. Order per iteration (pinned by sched_barrier):
//   waitcnt vmcnt(SOPS)      -- own stage(k) retired; stage(k+1) may fly
//   s_barrier (raw)          -- no compiler vmcnt(0) drain
//   W loads (vmem->reg)      -- oldest in queue
//   ds_read A from buf k%3
//   stage(k+2) -> buf (k+2)%3  -- youngest; survives the W-wait
//   MFMAs  (compiler emits vmcnt(SOPS) for W + lgkmcnt for ds_reads)
// stage(k+2) thus gets a full iteration (~500-600 cyc) before it is
// force-retired by iter k+1's W-wait -- covering L3-resident A latency.
// Buffer safety: buf (k+2)%3 was last ds_read in iter k-1; every wave's
// reads retire before it passes the iter-k barrier (forced by its own
// MFMAs' lgkm waits), and the stage is issued after that barrier.
template<bool PRECISE, bool WPRE, bool WF32>
__device__ __forceinline__ void staged_kloop(
    const unsigned short* __restrict__ Ahi, const unsigned short* __restrict__ Alo,
    const void* __restrict__ Wa, const void* __restrict__ Wb,
    unsigned short* sAhi, unsigned short* sAlo,   // [3][4096] ushorts each
    int m_blk0, int n_base, int wid, int lane, float4v acc[4][4])
{
    const int tid  = wid * 64 + lane;
    const int quad = lane >> 4, l16 = lane & 15;
    const int m_off = (wid >> 1) * 64;
    const int srow = tid >> 2;
    const int scc  = tid & 3;
    constexpr int NT = KDIM / 32;   // 24 tiles

    auto stage = [&](int kt, int b) {
#pragma unroll
        for (int it = 0; it < 2; it++) {
            const int r = it * 64 + srow;
            const size_t gidx = (size_t)(m_blk0 + r) * KDIM + kt * 32 + scc * 8;
            const int loff = b * 4096 + r * 32 + scc * 8;
            gload_lds16(Ahi + gidx, sAhi + loff);
            if constexpr (PRECISE) gload_lds16(Alo + gidx, sAlo + loff);
        }
    };

    stage(0, 0);
    stage(1, 1);

    for (int kt = 0; kt < NT; kt++) {
        const int b = kt % 3;
        // own stage(kt) retired; leave stage(kt+1) (SOPS ops) in flight
        if constexpr (PRECISE) asm volatile("s_waitcnt vmcnt(4)" ::: "memory");
        else                   asm volatile("s_waitcnt vmcnt(2)" ::: "memory");
        __builtin_amdgcn_s_barrier();
        asm volatile("" ::: "memory");   // no LDS reads hoisted above barrier

        // ---- W register loads (oldest vmem this iteration) ----
        short8 bh[4], bl[4];
#pragma unroll
        for (int in = 0; in < 4; in++) {
            const size_t widx = (size_t)(n_base + in * 16 + l16) * KDIM + kt * 32 + quad * 8;
            if constexpr (WPRE) {
                bh[in] = *(const short8*)((const unsigned short*)Wa + widx);
                if constexpr (PRECISE)
                    bl[in] = *(const short8*)((const unsigned short*)Wb + widx);
            } else {
                loadW<WF32, PRECISE>(Wa, widx, bh[in], bl[in]);
            }
        }
        // ---- A fragments from LDS buf b ----
        short8 ah[4], al[4];
#pragma unroll
        for (int im = 0; im < 4; im++) {
            const int r = m_off + im * 16 + l16;
            ah[im] = *(const short8*)(sAhi + b * 4096 + r * 32 + quad * 8);
            if constexpr (PRECISE) al[im] = *(const short8*)(sAlo + b * 4096 + r * 32 + quad * 8);
        }
        __builtin_amdgcn_sched_barrier(0);   // pin: loads above, stage below
        if (kt + 2 < NT) stage(kt + 2, (kt + 2) % 3);
        __builtin_amdgcn_sched_barrier(0);   // pin: stage issued before MFMAs
#pragma unroll
        for (int im = 0; im < 4; im++)
#pragma unroll
            for (int in = 0; in < 4; in++) {
                acc[im][in] = __builtin_amdgcn_mfma_f32_16x16x32_bf16(
                    ah[im], bh[in], acc[im][in], 0, 0, 0);
                if constexpr (PRECISE) {
                    acc[im][in] = __builtin_amdgcn_mfma_f32_16x16x32_bf16(
                        al[im], bh[in], acc[im][in], 0, 0, 0);
                    acc[im][in] = __builtin_amdgcn_mfma_f32_16x16x32_bf16(
                        ah[im], bl[in], acc[im][in], 0, 0, 0);
                }
            }
        // no trailing barrier: next iteration's waitcnt+barrier protects reuse
    }
}

// MODE 0: precise, +bias +rope *0.125*log2(e) -> hi/lo bf16 (B,H,S,D)  (Q)
// MODE 1: precise, +bias +rope               -> hi/lo bf16 (B,H,S,D)  (K)
// MODE 2: fast,    +bias                     -> bf16 V^T (B,H,D,S)
// MODE 3: fast,    +bias                     -> d_out (M,N), dtype per flag
template<int MODE, bool WPRE>
__device__ __forceinline__ void gemm_body(
    const unsigned short* __restrict__ Ahi, const unsigned short* __restrict__ Alo,
    const void* __restrict__ Wa, const void* __restrict__ Wb,
    const void* __restrict__ bias,
    const void* __restrict__ cosc, const void* __restrict__ sinc,
    const unsigned int* __restrict__ flag,
    void* __restrict__ Out, void* __restrict__ Out2,
    unsigned short* sAhi, unsigned short* sAlo,
    int m_blk0, int ny)
{
    constexpr bool PRECISE = (MODE <= 1);
    const int tid  = threadIdx.x;
    const int wid  = tid >> 6;
    const int lane = tid & 63;
    const int quad = lane >> 4;
    const int l16  = lane & 15;
    const int m_blk = m_blk0 + (wid >> 1) * 64;
    const int n_base = ny * 128 + (wid & 1) * 64;
    const bool f32 = (flag[0] != 0u);

    float4v acc[4][4];
#pragma unroll
    for (int i = 0; i < 4; i++)
#pragma unroll
        for (int j = 0; j < 4; j++) acc[i][j] = (float4v)(0.f);

    if constexpr (WPRE) {
        staged_kloop<PRECISE, true, false>(Ahi, Alo, Wa, Wb, sAhi, sAlo,
                                           m_blk0, n_base, wid, lane, acc);
    } else {
        if (f32) staged_kloop<PRECISE, false, true >(Ahi, Alo, Wa, Wb, sAhi, sAlo,
                                                     m_blk0, n_base, wid, lane, acc);
        else     staged_kloop<PRECISE, false, false>(Ahi, Alo, Wa, Wb, sAhi, sAlo,
                                                     m_blk0, n_base, wid, lane, acc);
    }

#pragma unroll
    for (int im = 0; im < 4; im++) {
#pragma unroll
        for (int in = 0; in < 4; in++) {
            const int col = n_base + in * 16 + l16;
            const float bval = loadf(bias, col, f32);
            if constexpr (MODE == 2) {
                short4v pk;
#pragma unroll
                for (int r = 0; r < 4; r++)
                    pk[r] = (short)f2bf(acc[im][in][r] + bval);
                const int row = m_blk + im * 16 + quad * 4;
                const int b = row >> 10, s = row & (SEQ - 1);
                const int h = col >> 6, d = col & (DH - 1);
                *(short4v*)((unsigned short*)Out +
                    ((size_t)(b * NH + h) * DH + d) * SEQ + s) = pk;
            } else if constexpr (MODE <= 1) {
                const int d  = col & (DH - 1);
                const int d2 = d >> 1;
#pragma unroll
                for (int r = 0; r < 4; r++) {
                    const int row = m_blk + im * 16 + quad * 4 + r;
                    const int s  = row & (SEQ - 1);
                    const float v = acc[im][in][r] + bval;
                    const float c  = loadf(cosc, s * (DH / 2) + d2, f32);
                    const float sn = loadf(sinc, s * (DH / 2) + d2, f32);
                    const float p = __shfl_xor(v, 1);  // lane^1 <-> d^1
                    float o = (d & 1) ? (v * c + p * sn) : (v * c - p * sn);
                    // Q scale folded with log2(e): logits live in log2 domain
                    if (MODE == 0) o *= 0.18033688f;   // 0.125 * 1.44269504
                    const float po = __shfl_xor(o, 1);
                    if (!(l16 & 1)) {
                        const unsigned short h0 = f2bf(o), h1 = f2bf(po);
                        const unsigned short l0 = f2bf(o - bf2f(h0));
                        const unsigned short l1 = f2bf(po - bf2f(h1));
                        const int b = row >> 10, h = col >> 6;
                        const size_t idx = ((size_t)(b * NH + h) * SEQ + s) * DH + d;
                        *(unsigned int*)((unsigned short*)Out + idx) =
                            (unsigned int)h0 | ((unsigned int)h1 << 16);
                        *(unsigned int*)((unsigned short*)Out2 + idx) =
                            (unsigned int)l0 | ((unsigned int)l1 << 16);
                    }
                }
            } else {
#pragma unroll
                for (int r = 0; r < 4; r++) {
                    const int row = m_blk + im * 16 + quad * 4 + r;
                    const float v = acc[im][in][r] + bval;
                    if (f32) ((float*)Out)[(size_t)row * HID + col] = v;
                    else     ((unsigned short*)Out)[(size_t)row * HID + col] = f2bf(v);
                }
            }
        }
    }
}

template<int MODE, bool WPRE>
__global__ __launch_bounds__(256) void gemm_staged(
    const unsigned short* __restrict__ Ahi, const unsigned short* __restrict__ Alo,
    const void* __restrict__ Wa, const void* __restrict__ Wb,
    const void* __restrict__ bias,
    const void* __restrict__ cosc, const void* __restrict__ sinc,
    const unsigned int* __restrict__ flag,
    void* __restrict__ Out, void* __restrict__ Out2)
{
    constexpr bool PRECISE = (MODE <= 1);
    __shared__ unsigned short sAhi[3 * 4096];
    __shared__ unsigned short sAlo[PRECISE ? 3 * 4096 : 64];
    gemm_body<MODE, WPRE>(Ahi, Alo, Wa, Wb, bias, cosc, sinc, flag, Out, Out2,
                          sAhi, sAlo, blockIdx.x * 128, blockIdx.y);
}

// Fused QKV GEMM: grid (M/128, 18); blockIdx.y/6 selects Q/K/V, %6 is the
// N-block. 2304 blocks (vs 3x768) — tail smoothing + concurrent A reuse in
// L2/L3 + 2 fewer launch gaps.
template<bool WPRE>
__global__ __launch_bounds__(256) void gemm_qkv(
    const unsigned short* __restrict__ Ahi, const unsigned short* __restrict__ Alo,
    const void* __restrict__ Wqa, const void* __restrict__ Wqb,
    const void* __restrict__ Wka, const void* __restrict__ Wkb,
    const void* __restrict__ Wva,
    const void* __restrict__ bq, const void* __restrict__ bk,
    const void* __restrict__ bv,
    const void* __restrict__ cosc, const void* __restrict__ sinc,
    const unsigned int* __restrict__ flag,
    void* __restrict__ Qhi, void* __restrict__ Qlo,
    void* __restrict__ Khi, void* __restrict__ Klo,
    void* __restrict__ Vt)
{
    __shared__ unsigned short sAhi[3 * 4096];
    __shared__ unsigned short sAlo[3 * 4096];
    const int which = blockIdx.y / 6;
    const int ny    = blockIdx.y % 6;
    const int m0    = blockIdx.x * 128;
    if (which == 0)
        gemm_body<0, WPRE>(Ahi, Alo, Wqa, Wqb, bq, cosc, sinc, flag,
                           Qhi, Qlo, sAhi, sAlo, m0, ny);
    else if (which == 1)
        gemm_body<1, WPRE>(Ahi, Alo, Wka, Wkb, bk, cosc, sinc, flag,
                           Khi, Klo, sAhi, sAlo, m0, ny);
    else
        gemm_body<2, WPRE>(Ahi, nullptr, Wva, nullptr, bv, nullptr, nullptr, flag,
                           Vt, nullptr, sAhi, sAlo, m0, ny);
}

// MFMA RSE attention v4: 4 waves/block, 64q each (256 q/block, 768 blocks).
// K/V per 32-key chunk staged ONCE per block via global_load_lds into a
// double-buffered, XOR-swizzled LDS slab; fragments via ds_read_b128.
// P routing is fully in-register: v_cvt_pk_bf16_f32 pack + permlane16/32
// swaps transpose {lane bits 4,5} <-> {register bits kt,h} — no P LDS slab,
// no software f2bf in the hot loop. Logits are computed in the log2 domain
// (log2e folded into the Q scale at GEMM time). Note: attn's MFMAs have no
// VMEM-register operands, so its dbuf does NOT suffer the vmcnt ordering
// trap — the prefetch survives until the end-of-iter barrier.
__global__ __launch_bounds__(256, 2) void attn_mfma(
    const unsigned short* __restrict__ Qhi, const unsigned short* __restrict__ Qlo,
    const unsigned short* __restrict__ Khi, const unsigned short* __restrict__ Klo,
    const unsigned short* __restrict__ Vt,   // (B*H, D, S) bf16
    const void* __restrict__ lam_p, const unsigned int* __restrict__ flag,
    unsigned short* __restrict__ ctx)        // (B, S, HID) bf16
{
    const int tid  = threadIdx.x;
    const int wid  = tid >> 6;
    const int lane = tid & 63;
    const int quad = lane >> 4;
    const int l16  = lane & 15;
    const int phys = blockIdx.x;                   // 768 blocks
    const int virt = (phys & 7) * 96 + (phys >> 3);  // XCD-contiguous bh runs
    const int bh   = virt >> 2;                    // 4 q-blocks per bh
    const int q0   = (virt & 3) * 256 + wid * 64;  // wave's query base
    const bool f32 = (flag[0] != 0u);
    // lam scaled into the log2 domain to match the pre-scaled Q
    const float lam2 = loadf(lam_p, 0, f32) * 1.44269504f;

    // [buf][ Khi 2048 | Klo 2048 | V 2048 ] ushorts (12KB per buffer)
    __shared__ unsigned short KV[2][6144];

    // staging thread mapping (whole block stages 12KB in 3 issues/thread)
    const int krow = tid >> 3, kch = tid & 7;
    const int kgch = kch ^ (krow & 7);             // XOR swizzle (read-side spread)
    const int vrow = tid >> 2, vch = tid & 3;
    const int vgch = vch ^ (vrow & 3);

    #define STAGE(kb_, buf_) do {                                            \
        const size_t gk = ((size_t)bh * SEQ + (kb_) * 32 + krow) * DH + kgch * 8; \
        gload_lds16(Khi + gk, &KV[buf_][0]    + tid * 8);                    \
        gload_lds16(Klo + gk, &KV[buf_][2048] + tid * 8);                    \
        const size_t gv = ((size_t)bh * DH + vrow) * SEQ + (kb_) * 32 + vgch * 8; \
        gload_lds16(Vt + gv, &KV[buf_][4096] + tid * 8);                     \
    } while (0)

    // resident Q fragments (B-operand), hi+lo
    short8 qh[4][2], ql[4][2];
#pragma unroll
    for (int qn = 0; qn < 4; qn++)
#pragma unroll
        for (int ks = 0; ks < 2; ks++) {
            const size_t base = ((size_t)bh * SEQ + (q0 + qn * 16 + l16)) * DH
                                + ks * 32 + quad * 8;
            qh[qn][ks] = *(const short8*)(Qhi + base);
            ql[qn][ks] = *(const short8*)(Qlo + base);
        }

    float4v acc_o[4][4];
#pragma unroll
    for (int i = 0; i < 4; i++)
#pragma unroll
        for (int j = 0; j < 4; j++) acc_o[i][j] = (float4v)(0.f);

    float rem[4] = {1.f, 1.f, 1.f, 1.f};
    float l_i[4] = {0.f, 0.f, 0.f, 0.f};
    float m_i[4] = {-INFINITY, -INFINITY, -INFINITY, -INFINITY};
    float qf[4];
#pragma unroll
    for (int qn = 0; qn < 4; qn++) qf[qn] = (float)(q0 + qn * 16 + l16);

    STAGE(0, 0);
    __syncthreads();

    for (int kb = 0; kb < SEQ / 32; kb++) {
        const int buf = kb & 1;
        if (kb + 1 < SEQ / 32) STAGE(kb + 1, buf ^ 1);

        // ---- K fragments from LDS (swizzled) ----
        short8 kh[2][2], kl[2][2];
#pragma unroll
        for (int kt = 0; kt < 2; kt++)
#pragma unroll
            for (int ks = 0; ks < 2; ks++) {
                const int off = (kt * 16 + l16) * 64
                                + ((ks * 4 + quad) ^ (l16 & 7)) * 8;
                kh[kt][ks] = *(const short8*)(&KV[buf][0]    + off);
                kl[kt][ks] = *(const short8*)(&KV[buf][2048] + off);
            }

        // ---- S^T = K·Q^T (bf16x3), log2-domain logits ----
        float4v s[2][4];
#pragma unroll
        for (int kt = 0; kt < 2; kt++)
#pragma unroll
            for (int qn = 0; qn < 4; qn++) s[kt][qn] = (float4v)(0.f);
#pragma unroll
        for (int ks = 0; ks < 2; ks++)
#pragma unroll
            for (int kt = 0; kt < 2; kt++)
#pragma unroll
                for (int qn = 0; qn < 4; qn++) {
                    s[kt][qn] = __builtin_amdgcn_mfma_f32_16x16x32_bf16(
                        kh[kt][ks], qh[qn][ks], s[kt][qn], 0, 0, 0);
                    s[kt][qn] = __builtin_amdgcn_mfma_f32_16x16x32_bf16(
                        kl[kt][ks], qh[qn][ks], s[kt][qn], 0, 0, 0);
                    s[kt][qn] = __builtin_amdgcn_mfma_f32_16x16x32_bf16(
                        kh[kt][ks], ql[qn][ks], s[kt][qn], 0, 0, 0);
                }

        // ---- sigmoid / decay / stats (log2 domain: no per-elem mul) ----
        float cons[4] = {0.f, 0.f, 0.f, 0.f};
        float mx[4] = {-INFINITY, -INFINITY, -INFINITY, -INFINITY};
#pragma unroll
        for (int kt = 0; kt < 2; kt++)
#pragma unroll
            for (int qn = 0; qn < 4; qn++)
#pragma unroll
                for (int r = 0; r < 4; r++) {
                    const float keyf = (float)(kb * 32 + kt * 16 + quad * 4 + r);
                    const float logit = s[kt][qn][r] - lam2 * fabsf(qf[qn] - keyf);
                    mx[qn] = fmaxf(mx[qn], logit);
                    const float beta = __builtin_amdgcn_rcpf(
                        1.f + fast_exp2(-logit));
                    const float w = beta * rem[qn];
                    cons[qn] += w;
                    s[kt][qn][r] = w;
                }
#pragma unroll
        for (int qn = 0; qn < 4; qn++) {
            cons[qn] += __shfl_xor(cons[qn], 16);
            cons[qn] += __shfl_xor(cons[qn], 32);
            mx[qn] = fmaxf(mx[qn], __shfl_xor(mx[qn], 16));
            mx[qn] = fmaxf(mx[qn], __shfl_xor(mx[qn], 32));
        }

        // ---- P^T B-fragments fully in-register ----
        short8 pf[4];
#pragma unroll
        for (int qn = 0; qn < 4; qn++) {
            const unsigned int d00 = cvt_pk_bf16(s[0][qn][0], s[0][qn][1]); // kt0 h0
            const unsigned int d01 = cvt_pk_bf16(s[0][qn][2], s[0][qn][3]); // kt0 h1
            const unsigned int d10 = cvt_pk_bf16(s[1][qn][0], s[1][qn][1]); // kt1 h0
            const unsigned int d11 = cvt_pk_bf16(s[1][qn][2], s[1][qn][3]); // kt1 h1
            auto r0 = __builtin_amdgcn_permlane32_swap(d00, d10, false, false);
            auto r1 = __builtin_amdgcn_permlane32_swap(d01, d11, false, false);
            auto t0 = __builtin_amdgcn_permlane16_swap(r0[0], r0[1], false, false);
            auto t1 = __builtin_amdgcn_permlane16_swap(r1[0], r1[1], false, false);
            union { unsigned int u[4]; short8 s8; } cv;
            cv.u[0] = t0[0];  // keys quad*8+{0,1}
            cv.u[1] = t1[0];  // keys quad*8+{2,3}
            cv.u[2] = t0[1];  // keys quad*8+{4,5}
            cv.u[3] = t1[1];  // keys quad*8+{6,7}
            pf[qn] = cv.s8;
        }

        // ---- O^T += V^T·P^T ----
        short8 vf[4];
#pragma unroll
        for (int dt = 0; dt < 4; dt++) {
            const int off = (dt * 16 + l16) * 32 + (quad ^ (l16 & 3)) * 8;
            vf[dt] = *(const short8*)(&KV[buf][4096] + off);
        }
#pragma unroll
        for (int dt = 0; dt < 4; dt++)
#pragma unroll
            for (int jn = 0; jn < 4; jn++)
                acc_o[dt][jn] = __builtin_amdgcn_mfma_f32_16x16x32_bf16(
                    vf[dt], pf[jn], acc_o[dt][jn], 0, 0, 0);

        // ---- state update (alpha converted back to raw-logit domain) ----
#pragma unroll
        for (int qn = 0; qn < 4; qn++) {
            rem[qn] = fmaxf(rem[qn] * (1.f - cons[qn]), 1e-6f);
            const float m_new = fmaxf(m_i[qn], mx[qn]);
            const float alpha = fast_exp2((m_i[qn] - m_new) * 0.69314718f);
            l_i[qn] = l_i[qn] * alpha + cons[qn];
            m_i[qn] = m_new;
        }

        __syncthreads();   // drains stage(kb+1) loads; protects buf reuse
    }

    const int b = bh / NH, h = bh % NH;
    float inv[4];
#pragma unroll
    for (int jn = 0; jn < 4; jn++)
        inv[jn] = __builtin_amdgcn_rcpf(fmaxf(l_i[jn], 1e-6f));
#pragma unroll
    for (int dt = 0; dt < 4; dt++)
#pragma unroll
        for (int jn = 0; jn < 4; jn++) {
            short4v pk;
#pragma unroll
            for (int r = 0; r < 4; r++)
                pk[r] = (short)f2bf(acc_o[dt][jn][r] * inv[jn]);
            const int q_g = q0 + jn * 16 + l16;
            *(short4v*)(ctx + ((size_t)(b * SEQ + q_g) * HID
                               + h * DH + dt * 16 + quad * 4)) = pk;
        }
    #undef STAGE
}

extern "C" void kernel_launch(void* const* d_in, const int* in_sizes, int n_in,
                              void* d_out, int out_size, void* d_ws, size_t ws_size,
                              hipStream_t stream) {
    const void* x    = d_in[0];
    const void* Wq   = d_in[1];
    const void* bq   = d_in[2];
    const void* Wk   = d_in[3];
    const void* bk   = d_in[4];
    const void* Wv   = d_in[5];
    const void* bv   = d_in[6];
    const void* Wo   = d_in[7];
    const void* bo   = d_in[8];
    const void* lam  = d_in[9];
    const void* cosc = d_in[10];
    const void* sinc = d_in[11];

    const size_t NELEM = (size_t)MTOT * HID;   // 12.58M
    const size_t WELEM = (size_t)HID * HID;    // 589824
    unsigned int* flag = (unsigned int*)d_ws;
    unsigned short* Xhi = (unsigned short*)((char*)d_ws + 64);
    unsigned short* Xlo = Xhi + NELEM;
    unsigned short* Qhi = Xlo + NELEM;
    unsigned short* Qlo = Qhi + NELEM;
    unsigned short* Wqh = Qlo + NELEM;   // W splits
    unsigned short* Wql = Wqh + WELEM;
    unsigned short* Wkh = Wql + WELEM;
    unsigned short* Wkl = Wkh + WELEM;
    unsigned short* Wvh = Wkl + WELEM;
    unsigned short* Woh = Wvh + WELEM;
    unsigned short* VtF = Woh + WELEM;   // fused-path V^T (must not alias Xlo)
    const size_t NEED  = 64 + 4 * NELEM * 2 + 6 * WELEM * 2;
    const size_t NEEDF = NEED + NELEM * 2;
    const bool wpre = (ws_size >= NEED);
    const bool fuse = (ws_size >= NEEDF);  // fuse implies wpre

    unsigned short* Vt  = fuse ? VtF : Xlo;  // sequential path: xlo dead after K GEMM
    unsigned short* Ctx = Xhi;               // xhi dead after V GEMM
    unsigned short* Khi = (unsigned short*)d_out;  // dead before final GEMM
    unsigned short* Klo = Khi + NELEM;

    detect_kernel<<<1, 256, 0, stream>>>((const unsigned short*)x, flag);
    split_ker<true><<<(MTOT * KDIM) / 2048, 256, 0, stream>>>(x, flag, Xhi, Xlo, MTOT * KDIM);

    dim3 gg(MTOT / 128, HID / 128), gb(256);
    if (fuse) {
        const int wb = (int)(WELEM / 2048);
        split_ker<true ><<<wb, 256, 0, stream>>>(Wq, flag, Wqh, Wql, (int)WELEM);
        split_ker<true ><<<wb, 256, 0, stream>>>(Wk, flag, Wkh, Wkl, (int)WELEM);
        split_ker<false><<<wb, 256, 0, stream>>>(Wv, flag, Wvh, nullptr, (int)WELEM);
        split_ker<false><<<wb, 256, 0, stream>>>(Wo, flag, Woh, nullptr, (int)WELEM);
        gemm_qkv<true><<<dim3(MTOT / 128, 18), gb, 0, stream>>>(
            Xhi, Xlo, Wqh, Wql, Wkh, Wkl, Wvh, bq, bk, bv,
            cosc, sinc, flag, Qhi, Qlo, Khi, Klo, VtF);
    } else if (wpre) {
        const int wb = (int)(WELEM / 2048);
        split_ker<true ><<<wb, 256, 0, stream>>>(Wq, flag, Wqh, Wql, (int)WELEM);
        split_ker<true ><<<wb, 256, 0, stream>>>(Wk, flag, Wkh, Wkl, (int)WELEM);
        split_ker<false><<<wb, 256, 0, stream>>>(Wv, flag, Wvh, nullptr, (int)WELEM);
        split_ker<false><<<wb, 256, 0, stream>>>(Wo, flag, Woh, nullptr, (int)WELEM);
        gemm_staged<0, true><<<gg, gb, 0, stream>>>(Xhi, Xlo, Wqh, Wql, bq, cosc, sinc, flag, Qhi, Qlo);
        gemm_staged<1, true><<<gg, gb, 0, stream>>>(Xhi, Xlo, Wkh, Wkl, bk, cosc, sinc, flag, Khi, Klo);
        gemm_staged<2, true><<<gg, gb, 0, stream>>>(Xhi, nullptr, Wvh, nullptr, bv, nullptr, nullptr, flag, Vt, nullptr);
    } else {
        gemm_staged<0, false><<<gg, gb, 0, stream>>>(Xhi, Xlo, Wq, nullptr, bq, cosc, sinc, flag, Qhi, Qlo);
        gemm_staged<1, false><<<gg, gb, 0, stream>>>(Xhi, Xlo, Wk, nullptr, bk, cosc, sinc, flag, Khi, Klo);
        gemm_staged<2, false><<<gg, gb, 0, stream>>>(Xhi, nullptr, Wv, nullptr, bv, nullptr, nullptr, flag, Vt, nullptr);
    }
    attn_mfma<<<dim3(4 * BATCH * NH), 256, 0, stream>>>(
        Qhi, Qlo, Khi, Klo, Vt, lam, flag, Ctx);
    if (wpre)
        gemm_staged<3, true><<<gg, gb, 0, stream>>>(Ctx, nullptr, Woh, nullptr, bo, nullptr, nullptr, flag, d_out, nullptr);
    else
        gemm_staged<3, false><<<gg, gb, 0, stream>>>(Ctx, nullptr, Wo, nullptr, bo, nullptr, nullptr, flag, d_out, nullptr);
}